// Round 15
// baseline (36.529 us; speedup 1.0000x reference)
//
#include <hip/hip_runtime.h>
#include <cfloat>

#define NEG_INF_F (-1e30f)

constexpr int BB = 8, SS = 4096, HH = 1024;
constexpr int TOTAL = BB * SS;   // 32768 rows
constexpr int MAXLEN = 30;
constexpr int TK_TPB = 1024;     // topk threads per block (16 waves)
constexpr int TK_RPB = 512;      // rows per topk block (2 threads/row)
constexpr int CPT = 15;          // candidates per thread (30/2)
constexpr int BLK_PER_B = SS / TK_RPB;       // 8 blocks per batch
constexpr int TK_GRID = BB * BLK_PER_B;      // 64 blocks

// ---------------- Kernel 1: QA-head GEMV + masking (proven ~20.5 us) ---------
// NOTE: plain __launch_bounds__(256) only — a min-waves hint caps VGPRs and
// serializes the 12 in-flight loads (R6/R8: 370 GB/s disaster).
__global__ __launch_bounds__(256) void qa_logits_kernel(
    const float* __restrict__ X,     // (B*S, H)
    const float* __restrict__ mask,  // (B*S)
    const float* __restrict__ W,     // (H, 2) row-major
    const float* __restrict__ bqa,   // (2)
    float* __restrict__ out,         // [0,TOTAL): start, [TOTAL,2*TOTAL): end
    unsigned* __restrict__ cnt) {    // (BB) ticket counters for topk
  if (blockIdx.x == 0 && threadIdx.x < BB) cnt[threadIdx.x] = 0u;
  int row  = (int)((blockIdx.x * (size_t)blockDim.x + threadIdx.x) >> 6);
  int lane = threadIdx.x & 63;
  if (row >= TOTAL) return;
  const float* rp = X + (size_t)row * HH;
  float s0 = 0.f, s1 = 0.f;
#pragma unroll
  for (int k = 0; k < HH / 256; ++k) {
    int h = (k * 64 + lane) * 4;
    const float4 x   = *reinterpret_cast<const float4*>(rp + h);
    const float4 w01 = *reinterpret_cast<const float4*>(W + 2 * h);
    const float4 w23 = *reinterpret_cast<const float4*>(W + 2 * h + 4);
    s0 += x.x * w01.x + x.y * w01.z + x.z * w23.x + x.w * w23.z;
    s1 += x.x * w01.y + x.y * w01.w + x.z * w23.y + x.w * w23.w;
  }
#pragma unroll
  for (int off = 32; off > 0; off >>= 1) {
    s0 += __shfl_down(s0, off);
    s1 += __shfl_down(s1, off);
  }
  if (lane == 0) {
    float m = mask[row];
    float inv = 1.f - m;
    out[row]         = (s0 + bqa[0]) * m + inv * NEG_INF_F;
    out[TOTAL + row] = (s1 + bqa[1]) * m + inv * NEG_INF_F;
  }
}

// ---------- packed u64 key: (sortable-float << 32) | (~idx) ----------
// Higher key = higher value, then lower flat index (jax top_k tie-break).
// Validated end-to-end in rounds 8-14.
__device__ __forceinline__ unsigned long long pack_key(float v, unsigned idx) {
  unsigned u = __float_as_uint(v);
  u = (u & 0x80000000u) ? ~u : (u | 0x80000000u);
  return ((unsigned long long)u << 32) | (unsigned long long)(0xFFFFFFFFu - idx);
}

// Sorted-descending 5-key insert, early exit (keys unique, 0 = sentinel).
__device__ __forceinline__ void k5_insert(unsigned long long k[5], unsigned long long nk) {
  if (nk <= k[4]) return;
  k[4] = nk;
  unsigned long long t;
  if (k[4] > k[3]) { t = k[3]; k[3] = k[4]; k[4] = t; }
  if (k[3] > k[2]) { t = k[2]; k[2] = k[3]; k[3] = t; }
  if (k[2] > k[1]) { t = k[1]; k[1] = k[2]; k[2] = t; }
  if (k[1] > k[0]) { t = k[0]; k[0] = k[1]; k[1] = t; }
}

// Wave-wide top-5 via 5 argmax rounds on u64 keys; result same in all lanes.
__device__ __forceinline__ void wave_top5_u64(unsigned long long k[5],
                                              unsigned long long r[5]) {
#pragma unroll
  for (int q = 0; q < 5; ++q) {
    unsigned long long m = k[0];
    if (k[1] > m) m = k[1];
    if (k[2] > m) m = k[2];
    if (k[3] > m) m = k[3];
    if (k[4] > m) m = k[4];
#pragma unroll
    for (int off = 1; off < 64; off <<= 1) {
      unsigned long long o = __shfl_xor(m, off);
      if (o > m) m = o;
    }
    r[q] = m;
#pragma unroll
    for (int p = 0; p < 5; ++p)
      if (k[p] == m) k[p] = 0ull;  // keys unique; invalidate winner
  }
}

// ---------------- Kernel 2: single-dispatch banded top-5 --------------------
// 64 blocks x 1024 threads; 8 blocks per batch -> ticket has only 8 RMWs per
// counter (R13's +7.4us was 64 RMWs/counter serialization). 512 rows/block,
// 2 threads/row x 15 candidates, direct L2 loads (R14-proven), in-block LDS
// merge of 16 waves, last block per batch merges 8x5=40 keys.
__global__ __launch_bounds__(TK_TPB) void topk_kernel(
    const float* __restrict__ logits,      // gemv output (start then end)
    float* __restrict__ out,
    unsigned long long* __restrict__ ws,   // (TK_GRID, 5) block top-5 keys
    unsigned* __restrict__ cnt) {          // (BB), zeroed by gemv
  const int t = (int)threadIdx.x;
  const int lane = t & 63;
  const int w = t >> 6;                    // wave 0..15
  const int b  = blockIdx.x >> 3;          // batch
  const int rb = blockIdx.x & 7;           // block within batch
  const int lr = t >> 1;                   // local row 0..511
  const int sub = t & 1;                   // window half
  const int i = rb * TK_RPB + lr;

  const float* st = logits + (size_t)b * SS;
  const float* en = logits + (size_t)(BB + b) * SS;

  __shared__ unsigned long long sk[(TK_TPB / 64) * 5];  // 80 keys

  unsigned long long k5[5] = {0, 0, 0, 0, 0};
  const float sv = st[i];                  // 2 lanes share -> broadcast fetch

  if (i >= 4) {
    const int c0 = sub * CPT;
    float e[CPT];
#pragma unroll
    for (int c = 0; c < CPT; ++c) {
      int j = i + c0 + c;
      // Unguarded load: max addr = 2*TOTAL+28 < out_size (65616).
      float v = en[j];
      e[c] = (j < SS) ? v : NEG_INF_F;     // c0+c <= 29 < MAXLEN always
    }
    unsigned base = (unsigned)(i * SS + i + c0);
#pragma unroll
    for (int c = 0; c < CPT; ++c) k5_insert(k5, pack_key(sv + e[c], base + c));
  } else if (i >= 1 && sub == 0) {         // spans (1,1),(2,2),(3,3)
    k5_insert(k5, pack_key(sv + en[i], (unsigned)(i * SS + i)));
  }

  unsigned long long r5[5];
  wave_top5_u64(k5, r5);
  if (lane == 0) {
#pragma unroll
    for (int q = 0; q < 5; ++q) sk[w * 5 + q] = r5[q];
  }
  __syncthreads();

  if (w == 0) {  // wave 0: merge 16 waves * 5 = 80 keys -> block top-5
    unsigned long long m5[5] = {0, 0, 0, 0, 0};
    m5[0] = sk[lane];
    if (lane < (TK_TPB / 64) * 5 - 64) m5[1] = sk[64 + lane];
    unsigned long long f5[5];
    wave_top5_u64(m5, f5);

    // publish block result + ticket (8 RMWs per counter)
    unsigned old = 0;
    if (lane == 0) {
#pragma unroll
      for (int q = 0; q < 5; ++q)
        __hip_atomic_store(&ws[blockIdx.x * 5 + q], f5[q],
                           __ATOMIC_RELAXED, __HIP_MEMORY_SCOPE_AGENT);
      __threadfence();  // release: block result visible before ticket
      old = __hip_atomic_fetch_add(&cnt[b], 1u, __ATOMIC_RELAXED,
                                   __HIP_MEMORY_SCOPE_AGENT);
    }
    old = __shfl(old, 0);

    if (old == (unsigned)(BLK_PER_B - 1)) {  // last block of batch b
      __threadfence();                       // acquire
      const unsigned long long* src = ws + (size_t)b * BLK_PER_B * 5;  // 40
      unsigned long long g5[5] = {0, 0, 0, 0, 0};
      if (lane < BLK_PER_B * 5)
        g5[0] = __hip_atomic_load(&src[lane], __ATOMIC_RELAXED,
                                  __HIP_MEMORY_SCOPE_AGENT);
      unsigned long long h5[5];
      wave_top5_u64(g5, h5);
      if (lane == 0) {
        float* ts = out + 2 * (size_t)TOTAL;  // top_start region
        float* te = ts + BB * 5;              // top_end region
#pragma unroll
        for (int q = 0; q < 5; ++q) {
          unsigned idx = 0xFFFFFFFFu - (unsigned)(h5[q] & 0xFFFFFFFFull);
          ts[b * 5 + q] = (float)(idx >> 12);       // idx / S  (S=4096)
          te[b * 5 + q] = (float)(idx & (SS - 1));  // idx % S
        }
      }
    }
  }
}

extern "C" void kernel_launch(void* const* d_in, const int* in_sizes, int n_in,
                              void* d_out, int out_size, void* d_ws, size_t ws_size,
                              hipStream_t stream) {
  const float* X    = (const float*)d_in[0];  // (B,S,H)
  const float* mask = (const float*)d_in[1];  // (B,S)
  const float* W    = (const float*)d_in[2];  // (H,2)
  const float* bqa  = (const float*)d_in[3];  // (2)
  float* out = (float*)d_out;

  unsigned long long* ws = (unsigned long long*)d_ws;  // TK_GRID*5 u64
  unsigned* cnt = (unsigned*)((char*)d_ws + TK_GRID * 5 * sizeof(unsigned long long));

  qa_logits_kernel<<<TOTAL / 4, 256, 0, stream>>>(X, mask, W, bqa, out, cnt);
  topk_kernel<<<TK_GRID, TK_TPB, 0, stream>>>(out, out, ws, cnt);
}